// Round 13
// baseline (45.087 us; speedup 1.0000x reference)
//
#include <hip/hip_runtime.h>

#define ROWS 256
#define COLS 512
#define BATCH 512
#define NC 5
#define DEG 16
#define EPG (ROWS * DEG)       /* 4096 edges per graph */
#define NPG (ROWS + COLS)      /* 768 nodes per graph  */
#define NT 512
#define EPT (EPG / NT)         /* 8 edges per thread   */
#define EPSF 1e-7f
/* slot p -> word 10*(p>>3) + (p&7): 2 pad words per 8; lane-stride-10 => 2-way (free) */
#define SWZ(p) (((p) >> 3) * 10 + ((p) & 7))
#define MSGW (EPG / 8 * 10)

typedef unsigned int u32;
typedef float v2f __attribute__((ext_vector_type(2)));

__device__ __forceinline__ float sigmoid_f(float a) {
    return 1.0f / (1.0f + __expf(-a));
}
__device__ __forceinline__ float tanh_f(float a) {
    return fmaf(2.0f, 1.0f / (1.0f + __expf(-2.0f * a)), -1.0f);
}

__global__ __launch_bounds__(NT, 4) void gnni_kernel(
    const float* __restrict__ x,
    const int*   __restrict__ eidx,
    const float* __restrict__ w1_1, const float* __restrict__ b1_1,
    const float* __restrict__ w2_1, const float* __restrict__ b2_1,
    const float* __restrict__ wih_1, const float* __restrict__ whh_1,
    const float* __restrict__ bih_1, const float* __restrict__ bhh_1,
    const float* __restrict__ w1_2, const float* __restrict__ b1_2,
    const float* __restrict__ w2_2, const float* __restrict__ b2_2,
    const float* __restrict__ wih_2, const float* __restrict__ whh_2,
    const float* __restrict__ bih_2, const float* __restrict__ bhh_2,
    float* __restrict__ out)
{
    __shared__ u32  e1[EPG];       // edges sorted by dst (packed s | d<<16)
    __shared__ u32  e2[EPG];       // edges sorted by src
    __shared__ float msg[MSGW];    // swizzled per-edge messages
    __shared__ u32  cntd[COLS];
    __shared__ u32  cnts[ROWS];
    __shared__ unsigned short ofs_v[COLS + 1];
    __shared__ unsigned short ofs_c[ROWS + 1];
    __shared__ float hc[ROWS];
    __shared__ float hv[COLS];
    __shared__ u32  wsum[8];
    __shared__ u32  wsum2[4];

    const int tid  = threadIdx.x;
    const int lane = tid & 63;
    const int wid  = tid >> 6;
    const int b    = blockIdx.x;
    const int base = b * NPG;
    const long ebase = (long)b * EPG;

    // ---- vectorized edge load ----
    const int4 sa = *(const int4*)(eidx + ebase + tid * 8);
    const int4 sb = *(const int4*)(eidx + ebase + tid * 8 + 4);
    const int4 da = *(const int4*)(eidx + (long)BATCH * EPG + ebase + tid * 8);
    const int4 db = *(const int4*)(eidx + (long)BATCH * EPG + ebase + tid * 8 + 4);
    const int sarr[EPT] = {sa.x, sa.y, sa.z, sa.w, sb.x, sb.y, sb.z, sb.w};
    const int darr[EPT] = {da.x, da.y, da.z, da.w, db.x, db.y, db.z, db.w};
    u32 ep[EPT];
    #pragma unroll
    for (int i = 0; i < EPT; ++i)
        ep[i] = (u32)(sarr[i] - base) | ((u32)(darr[i] - base) << 16);

    // ---- count both keys ----
    cntd[tid] = 0;
    if (tid < ROWS) cnts[tid] = 0;
    __syncthreads();
    #pragma unroll
    for (int i = 0; i < EPT; ++i) {
        atomicAdd(&cntd[ep[i] >> 16], 1u);
        atomicAdd(&cnts[ep[i] & 0xffffu], 1u);
    }
    __syncthreads();

    // ---- wave-shuffle scans -> exclusive cursors + CSR offsets ----
    u32 myd = cntd[tid];
    u32 scv = myd;
    #pragma unroll
    for (int st = 1; st < 64; st <<= 1) {
        u32 t = __shfl_up(scv, st);
        if (lane >= st) scv += t;
    }
    if (lane == 63) wsum[wid] = scv;
    u32 mys = 0, scc = 0;
    if (tid < ROWS) {
        mys = cnts[tid];
        scc = mys;
        #pragma unroll
        for (int st = 1; st < 64; st <<= 1) {
            u32 t = __shfl_up(scc, st);
            if (lane >= st) scc += t;
        }
        if (lane == 63) wsum2[wid] = scc;
    }
    __syncthreads();
    if (tid < 8) {
        u32 v = wsum[tid];
        #pragma unroll
        for (int st = 1; st < 8; st <<= 1) {
            u32 t = __shfl_up(v, st);
            if (tid >= st) v += t;
        }
        wsum[tid] = v;
    } else if (tid < 12) {
        u32 v = wsum2[tid - 8];
        #pragma unroll
        for (int st = 1; st < 4; st <<= 1) {
            u32 t = __shfl_up(v, st);
            if (tid - 8 >= st) v += t;
        }
        wsum2[tid - 8] = v;
    }
    __syncthreads();
    {
        u32 inc = scv + (wid ? wsum[wid - 1] : 0u);
        ofs_v[tid + 1] = (unsigned short)inc;
        if (tid == 0) ofs_v[0] = 0;
        cntd[tid] = inc - myd;
    }
    if (tid < ROWS) {
        u32 inc = scc + (wid ? wsum2[wid - 1] : 0u);
        ofs_c[tid + 1] = (unsigned short)inc;
        if (tid == 0) ofs_c[0] = 0;
        cnts[tid] = inc - mys;
        hc[tid] = x[base + tid];
    }
    float hvreg = x[base + ROWS + tid];
    hv[tid] = hvreg;
    __syncthreads();

    // ---- scatter edges into sorted order (one-time) ----
    #pragma unroll
    for (int i = 0; i < EPT; ++i) {
        u32 p = ep[i];
        u32 pos = atomicAdd(&cntd[p >> 16], 1u);
        e1[pos] = p;
        u32 pos2 = atomicAdd(&cnts[p & 0xffffu], 1u);
        e2[pos2] = p;
    }
    __syncthreads();

    // ---- read back 8 consecutive sorted edges per thread (b128) ----
    u32 d1[EPT], s1[EPT], d2[EPT], s2[EPT];
    {
        const uint4 q0 = *(const uint4*)&e1[tid * 8];
        const uint4 q1 = *(const uint4*)&e1[tid * 8 + 4];
        const uint4 r0 = *(const uint4*)&e2[tid * 8];
        const uint4 r1 = *(const uint4*)&e2[tid * 8 + 4];
        const u32 eq1[EPT] = {q0.x,q0.y,q0.z,q0.w,q1.x,q1.y,q1.z,q1.w};
        const u32 eq2[EPT] = {r0.x,r0.y,r0.z,r0.w,r1.x,r1.y,r1.z,r1.w};
        #pragma unroll
        for (int i = 0; i < EPT; ++i) {
            d1[i] = eq1[i] >> 16;  s1[i] = eq1[i] & 0xffffu;
            d2[i] = eq2[i] >> 16;  s2[i] = eq2[i] & 0xffffu;
        }
    }

    // ---- weights as float2 pairs (wave-uniform -> SGPRs) ----
    v2f A1[5], C1[5], B1[5], W1[5], A2[5], C2[5], B2[5], W2[5];
    #pragma unroll
    for (int j = 0; j < 5; ++j) {
        A1[j] = (v2f){w1_1[4*j],     w1_1[4*j + 2]};
        C1[j] = (v2f){w1_1[4*j + 1], w1_1[4*j + 3]};
        B1[j] = (v2f){b1_1[2*j],     b1_1[2*j + 1]};
        W1[j] = (v2f){w2_1[2*j],     w2_1[2*j + 1]};
        A2[j] = (v2f){w1_2[4*j],     w1_2[4*j + 2]};
        C2[j] = (v2f){w1_2[4*j + 1], w1_2[4*j + 3]};
        B2[j] = (v2f){b1_2[2*j],     b1_2[2*j + 1]};
        W2[j] = (v2f){w2_2[2*j],     w2_2[2*j + 1]};
    }
    const float b2_1s = b2_1[0], b2_2s = b2_2[0];
    const v2f zero2 = (v2f){0.0f, 0.0f};
    float2* const mbase = (float2*)&msg[tid * 10];   // thread-owned slots, 8B aligned

    for (int it = 0; it < NC; ++it) {
        // ===== phase 1 pass A: 8 independent MLPs -> coalesced float2 writes =====
        {
            float m[EPT];
            #pragma unroll
            for (int i = 0; i < EPT; ++i) {
                const float xj = hc[s1[i]];
                const float xi = hv[d1[i]];
                const v2f xj2 = (v2f){xj, xj}, xi2 = (v2f){xi, xi};
                v2f acc = (v2f){b2_1s, 0.0f};
                #pragma unroll
                for (int j = 0; j < 5; ++j) {
                    v2f t = __builtin_elementwise_fma(C1[j], xi2, B1[j]);
                    t = __builtin_elementwise_fma(A1[j], xj2, t);
                    t = __builtin_elementwise_max(t, zero2);
                    acc = __builtin_elementwise_fma(W1[j], t, acc);
                }
                m[i] = acc.x + acc.y;
            }
            mbase[0] = (float2){m[0], m[1]};
            mbase[1] = (float2){m[2], m[3]};
            mbase[2] = (float2){m[4], m[5]};
            mbase[3] = (float2){m[6], m[7]};
        }
        __syncthreads();

        // ===== phase 1 pass B: var owner swizzled CSR gather + GRU =====
        {
            const int beg = ofs_v[tid], end = ofs_v[tid + 1];
            float hx = 0.0f;
            for (int e = beg; e < end; ++e) hx += msg[SWZ(e)];
            const float xg = hvreg;
            float gi0 = fmaf(wih_1[0], xg, bih_1[0]);
            float gi1 = fmaf(wih_1[1], xg, bih_1[1]);
            float gi2 = fmaf(wih_1[2], xg, bih_1[2]);
            float gh0 = fmaf(whh_1[0], hx, bhh_1[0]);
            float gh1 = fmaf(whh_1[1], hx, bhh_1[1]);
            float gh2 = fmaf(whh_1[2], hx, bhh_1[2]);
            float r = sigmoid_f(gi0 + gh0);
            float z = sigmoid_f(gi1 + gh1);
            float n = tanh_f(fmaf(r, gh2, gi2));
            hvreg = fmaf(1.0f - z, n, z * hx);
            hv[tid] = hvreg;
        }
        __syncthreads();

        // ===== phase 2 pass A: 8 independent MLPs -> coalesced float2 writes =====
        {
            float m[EPT];
            #pragma unroll
            for (int i = 0; i < EPT; ++i) {
                const float xj = hv[d2[i]];
                const float xi = hc[s2[i]];
                const v2f xj2 = (v2f){xj, xj}, xi2 = (v2f){xi, xi};
                v2f acc = (v2f){b2_2s, 0.0f};
                #pragma unroll
                for (int j = 0; j < 5; ++j) {
                    v2f t = __builtin_elementwise_fma(C2[j], xi2, B2[j]);
                    t = __builtin_elementwise_fma(A2[j], xj2, t);
                    t = __builtin_elementwise_max(t, zero2);
                    acc = __builtin_elementwise_fma(W2[j], t, acc);
                }
                m[i] = acc.x + acc.y;
            }
            mbase[0] = (float2){m[0], m[1]};
            mbase[1] = (float2){m[2], m[3]};
            mbase[2] = (float2){m[4], m[5]};
            mbase[3] = (float2){m[6], m[7]};
        }
        __syncthreads();

        // ===== phase 2 pass B: lane-pair per check node, swizzled gather =====
        {
            const int c    = tid >> 1;
            const int half = tid & 1;
            const int beg = ofs_c[c], end = ofs_c[c + 1];
            const int h0  = (end - beg + 1) >> 1;
            const int lo  = half ? (beg + h0) : beg;
            const int hi  = half ? end : (beg + h0);
            float part = 0.0f;
            for (int e = lo; e < hi; ++e) part += msg[SWZ(e)];
            part += __shfl_xor(part, 1);
            if (half == 0) {
                const float hx = part;
                const float xg = hc[c];
                float gi0 = fmaf(wih_2[0], xg, bih_2[0]);
                float gi1 = fmaf(wih_2[1], xg, bih_2[1]);
                float gi2 = fmaf(wih_2[2], xg, bih_2[2]);
                float gh0 = fmaf(whh_2[0], hx, bhh_2[0]);
                float gh1 = fmaf(whh_2[1], hx, bhh_2[1]);
                float gh2 = fmaf(whh_2[2], hx, bhh_2[2]);
                float r = sigmoid_f(gi0 + gh0);
                float z = sigmoid_f(gi1 + gh1);
                float n = tanh_f(fmaf(r, gh2, gi2));
                hc[c] = fmaf(1.0f - z, n, z * hx);
            }
        }
        __syncthreads();
    }

    // ---- epilogue: out = clip(sigmoid(-h), eps, 1-eps) ----
    {
        float sgm = 1.0f / (1.0f + __expf(hvreg));
        out[base + ROWS + tid] = fminf(fmaxf(sgm, EPSF), 1.0f - EPSF);
    }
    if (tid < ROWS) {
        float sgm = 1.0f / (1.0f + __expf(hc[tid]));
        out[base + tid] = fminf(fmaxf(sgm, EPSF), 1.0f - EPSF);
    }
}

extern "C" void kernel_launch(void* const* d_in, const int* in_sizes, int n_in,
                              void* d_out, int out_size, void* d_ws, size_t ws_size,
                              hipStream_t stream) {
    const float* x    = (const float*)d_in[0];
    const int*   eidx = (const int*)d_in[1];
    gnni_kernel<<<BATCH, NT, 0, stream>>>(
        x, eidx,
        (const float*)d_in[2],  (const float*)d_in[3],
        (const float*)d_in[4],  (const float*)d_in[5],
        (const float*)d_in[6],  (const float*)d_in[7],
        (const float*)d_in[8],  (const float*)d_in[9],
        (const float*)d_in[10], (const float*)d_in[11],
        (const float*)d_in[12], (const float*)d_in[13],
        (const float*)d_in[14], (const float*)d_in[15],
        (const float*)d_in[16], (const float*)d_in[17],
        (float*)d_out);
}

// Round 14
// 41.942 us; speedup vs baseline: 1.0750x; 1.0750x over previous
//
#include <hip/hip_runtime.h>

#define ROWS 256
#define COLS 512
#define BATCH 512
#define NC 5
#define DEG 16
#define EPG (ROWS * DEG)       /* 4096 edges per graph */
#define NPG (ROWS + COLS)      /* 768 nodes per graph  */
#define NT 512
#define EPT (EPG / NT)         /* 8 edges per thread   */
#define EPSF 1e-7f

typedef unsigned short u16;
typedef unsigned int   u32;
typedef float v2f __attribute__((ext_vector_type(2)));

__device__ __forceinline__ float sigmoid_f(float a) {
    return 1.0f / (1.0f + __expf(-a));
}
__device__ __forceinline__ float tanh_f(float a) {
    return fmaf(2.0f, 1.0f / (1.0f + __expf(-2.0f * a)), -1.0f);
}

__global__ __launch_bounds__(NT, 4) void gnni_kernel(
    const float* __restrict__ x,
    const int*   __restrict__ eidx,
    const float* __restrict__ w1_1, const float* __restrict__ b1_1,
    const float* __restrict__ w2_1, const float* __restrict__ b2_1,
    const float* __restrict__ wih_1, const float* __restrict__ whh_1,
    const float* __restrict__ bih_1, const float* __restrict__ bhh_1,
    const float* __restrict__ w1_2, const float* __restrict__ b1_2,
    const float* __restrict__ w2_2, const float* __restrict__ b2_2,
    const float* __restrict__ wih_2, const float* __restrict__ whh_2,
    const float* __restrict__ bih_2, const float* __restrict__ bhh_2,
    float* __restrict__ out)
{
    __shared__ float msg[EPG];        // per-edge messages (both phases)
    __shared__ u32  cntd[COLS];       // dst counts -> placement cursor
    __shared__ u32  cnts[ROWS];       // src counts -> placement cursor
    __shared__ u16  ofs_v[COLS + 1];  // CSR offsets per var node
    __shared__ u16  ofs_c[ROWS + 1];  // CSR offsets per check node
    __shared__ float hc[ROWS];
    __shared__ float hv[COLS];
    __shared__ u32  wsum[8];          // per-wave scan partials (dst)
    __shared__ u32  wsum2[4];         // per-wave scan partials (src)

    const int tid  = threadIdx.x;
    const int lane = tid & 63;
    const int wid  = tid >> 6;
    const int b    = blockIdx.x;
    const int base = b * NPG;
    const long ebase = (long)b * EPG;

    // ---- vectorized edge load: thread tid owns edges [tid*8, tid*8+8) ----
    const int4 sa = *(const int4*)(eidx + ebase + tid * 8);
    const int4 sb = *(const int4*)(eidx + ebase + tid * 8 + 4);
    const int4 da = *(const int4*)(eidx + (long)BATCH * EPG + ebase + tid * 8);
    const int4 db = *(const int4*)(eidx + (long)BATCH * EPG + ebase + tid * 8 + 4);
    const int sarr[EPT] = {sa.x, sa.y, sa.z, sa.w, sb.x, sb.y, sb.z, sb.w};
    const int darr[EPT] = {da.x, da.y, da.z, da.w, db.x, db.y, db.z, db.w};
    u32 ep[EPT];
    #pragma unroll
    for (int i = 0; i < EPT; ++i)
        ep[i] = (u32)(sarr[i] - base) | ((u32)(darr[i] - base) << 16);

    // ---- count both keys ----
    cntd[tid] = 0;
    if (tid < ROWS) cnts[tid] = 0;
    __syncthreads();
    #pragma unroll
    for (int i = 0; i < EPT; ++i) {
        atomicAdd(&cntd[ep[i] >> 16], 1u);
        atomicAdd(&cnts[ep[i] & 0xffffu], 1u);
    }
    __syncthreads();

    // ---- wave-shuffle scans -> exclusive cursors + CSR offsets ----
    u32 myd = cntd[tid];
    u32 scv = myd;
    #pragma unroll
    for (int st = 1; st < 64; st <<= 1) {
        u32 t = __shfl_up(scv, st);
        if (lane >= st) scv += t;
    }
    if (lane == 63) wsum[wid] = scv;
    u32 mys = 0, scc = 0;
    if (tid < ROWS) {
        mys = cnts[tid];
        scc = mys;
        #pragma unroll
        for (int st = 1; st < 64; st <<= 1) {
            u32 t = __shfl_up(scc, st);
            if (lane >= st) scc += t;
        }
        if (lane == 63) wsum2[wid] = scc;
    }
    __syncthreads();
    if (tid < 8) {
        u32 v = wsum[tid];
        #pragma unroll
        for (int st = 1; st < 8; st <<= 1) {
            u32 t = __shfl_up(v, st);
            if (tid >= st) v += t;
        }
        wsum[tid] = v;
    } else if (tid < 12) {
        u32 v = wsum2[tid - 8];
        #pragma unroll
        for (int st = 1; st < 4; st <<= 1) {
            u32 t = __shfl_up(v, st);
            if (tid - 8 >= st) v += t;
        }
        wsum2[tid - 8] = v;
    }
    __syncthreads();
    {
        u32 inc = scv + (wid ? wsum[wid - 1] : 0u);
        ofs_v[tid + 1] = (u16)inc;
        if (tid == 0) ofs_v[0] = 0;
        cntd[tid] = inc - myd;                         // exclusive cursor
    }
    if (tid < ROWS) {
        u32 inc = scc + (wid ? wsum2[wid - 1] : 0u);
        ofs_c[tid + 1] = (u16)inc;
        if (tid == 0) ofs_c[0] = 0;
        cnts[tid] = inc - mys;
        hc[tid] = x[base + tid];
    }
    float hvreg = x[base + ROWS + tid];
    hv[tid] = hvreg;
    __syncthreads();

    // ---- placement: record per-edge sorted positions in registers ----
    u32 pos1[EPT], pos2[EPT];
    #pragma unroll
    for (int i = 0; i < EPT; ++i) {
        pos1[i] = atomicAdd(&cntd[ep[i] >> 16], 1u);
        pos2[i] = atomicAdd(&cnts[ep[i] & 0xffffu], 1u);
    }

    // ---- weights as float2 pairs (wave-uniform -> SGPRs) ----
    v2f A1[5], C1[5], B1[5], W1[5], A2[5], C2[5], B2[5], W2[5];
    #pragma unroll
    for (int j = 0; j < 5; ++j) {
        A1[j] = (v2f){w1_1[4*j],     w1_1[4*j + 2]};
        C1[j] = (v2f){w1_1[4*j + 1], w1_1[4*j + 3]};
        B1[j] = (v2f){b1_1[2*j],     b1_1[2*j + 1]};
        W1[j] = (v2f){w2_1[2*j],     w2_1[2*j + 1]};
        A2[j] = (v2f){w1_2[4*j],     w1_2[4*j + 2]};
        C2[j] = (v2f){w1_2[4*j + 1], w1_2[4*j + 3]};
        B2[j] = (v2f){b1_2[2*j],     b1_2[2*j + 1]};
        W2[j] = (v2f){w2_2[2*j],     w2_2[2*j + 1]};
    }
    const float b2_1s = b2_1[0], b2_2s = b2_2[0];
    const v2f zero2 = (v2f){0.0f, 0.0f};

    for (int it = 0; it < NC; ++it) {
        // ===== phase 1 pass A: balanced edge-parallel MLP, scatter to msg =====
        #pragma unroll
        for (int i = 0; i < EPT; ++i) {
            const u32 p = ep[i];
            const float xj = hc[p & 0xffffu];
            const float xi = hv[p >> 16];
            const v2f xj2 = (v2f){xj, xj}, xi2 = (v2f){xi, xi};
            v2f acc = (v2f){b2_1s, 0.0f};
            #pragma unroll
            for (int j = 0; j < 5; ++j) {
                v2f t = __builtin_elementwise_fma(C1[j], xi2, B1[j]);
                t = __builtin_elementwise_fma(A1[j], xj2, t);
                t = __builtin_elementwise_max(t, zero2);
                acc = __builtin_elementwise_fma(W1[j], t, acc);
            }
            msg[pos1[i]] = acc.x + acc.y;
        }
        __syncthreads();

        // ===== phase 1 pass B: var owner — UNROLLED predicated gather + GRU =====
        {
            const int beg = ofs_v[tid], end = ofs_v[tid + 1];
            float a0 = 0.0f, a1 = 0.0f, a2 = 0.0f, a3 = 0.0f;
            #pragma unroll
            for (int k = 0; k < 16; k += 4) {
                if (beg + k     < end) a0 += msg[beg + k];
                if (beg + k + 1 < end) a1 += msg[beg + k + 1];
                if (beg + k + 2 < end) a2 += msg[beg + k + 2];
                if (beg + k + 3 < end) a3 += msg[beg + k + 3];
            }
            float hx = (a0 + a1) + (a2 + a3);
            for (int e = beg + 16; e < end; ++e) hx += msg[e];  // rare: deg>16
            const float xg = hvreg;
            float gi0 = fmaf(wih_1[0], xg, bih_1[0]);
            float gi1 = fmaf(wih_1[1], xg, bih_1[1]);
            float gi2 = fmaf(wih_1[2], xg, bih_1[2]);
            float gh0 = fmaf(whh_1[0], hx, bhh_1[0]);
            float gh1 = fmaf(whh_1[1], hx, bhh_1[1]);
            float gh2 = fmaf(whh_1[2], hx, bhh_1[2]);
            float r = sigmoid_f(gi0 + gh0);
            float z = sigmoid_f(gi1 + gh1);
            float n = tanh_f(fmaf(r, gh2, gi2));
            hvreg = fmaf(1.0f - z, n, z * hx);
            hv[tid] = hvreg;
        }
        __syncthreads();

        // ===== phase 2 pass A: balanced edge-parallel MLP (fresh hv) =====
        #pragma unroll
        for (int i = 0; i < EPT; ++i) {
            const u32 p = ep[i];
            const float xi = hc[p & 0xffffu];
            const float xj = hv[p >> 16];
            const v2f xj2 = (v2f){xj, xj}, xi2 = (v2f){xi, xi};
            v2f acc = (v2f){b2_2s, 0.0f};
            #pragma unroll
            for (int j = 0; j < 5; ++j) {
                v2f t = __builtin_elementwise_fma(C2[j], xi2, B2[j]);
                t = __builtin_elementwise_fma(A2[j], xj2, t);
                t = __builtin_elementwise_max(t, zero2);
                acc = __builtin_elementwise_fma(W2[j], t, acc);
            }
            msg[pos2[i]] = acc.x + acc.y;
        }
        __syncthreads();

        // ===== phase 2 pass B: lane-pair per check — UNROLLED predicated gather =====
        {
            const int c    = tid >> 1;
            const int half = tid & 1;
            const int beg = ofs_c[c], end = ofs_c[c + 1];
            const int h0  = (end - beg + 1) >> 1;
            const int lo  = half ? (beg + h0) : beg;
            const int hi  = half ? end : (beg + h0);
            float a0 = 0.0f, a1 = 0.0f, a2 = 0.0f, a3 = 0.0f;
            #pragma unroll
            for (int k = 0; k < 16; k += 4) {
                if (lo + k     < hi) a0 += msg[lo + k];
                if (lo + k + 1 < hi) a1 += msg[lo + k + 1];
                if (lo + k + 2 < hi) a2 += msg[lo + k + 2];
                if (lo + k + 3 < hi) a3 += msg[lo + k + 3];
            }
            float part = (a0 + a1) + (a2 + a3);
            for (int e = lo + 16; e < hi; ++e) part += msg[e];  // rare: half>16
            part += __shfl_xor(part, 1);
            if (half == 0) {
                const float hx = part;
                const float xg = hc[c];
                float gi0 = fmaf(wih_2[0], xg, bih_2[0]);
                float gi1 = fmaf(wih_2[1], xg, bih_2[1]);
                float gi2 = fmaf(wih_2[2], xg, bih_2[2]);
                float gh0 = fmaf(whh_2[0], hx, bhh_2[0]);
                float gh1 = fmaf(whh_2[1], hx, bhh_2[1]);
                float gh2 = fmaf(whh_2[2], hx, bhh_2[2]);
                float r = sigmoid_f(gi0 + gh0);
                float z = sigmoid_f(gi1 + gh1);
                float n = tanh_f(fmaf(r, gh2, gi2));
                hc[c] = fmaf(1.0f - z, n, z * hx);
            }
        }
        __syncthreads();
    }

    // ---- epilogue: out = clip(sigmoid(-h), eps, 1-eps) ----
    {
        float sgm = 1.0f / (1.0f + __expf(hvreg));
        out[base + ROWS + tid] = fminf(fmaxf(sgm, EPSF), 1.0f - EPSF);
    }
    if (tid < ROWS) {
        float sgm = 1.0f / (1.0f + __expf(hc[tid]));
        out[base + tid] = fminf(fmaxf(sgm, EPSF), 1.0f - EPSF);
    }
}

extern "C" void kernel_launch(void* const* d_in, const int* in_sizes, int n_in,
                              void* d_out, int out_size, void* d_ws, size_t ws_size,
                              hipStream_t stream) {
    const float* x    = (const float*)d_in[0];
    const int*   eidx = (const int*)d_in[1];
    gnni_kernel<<<BATCH, NT, 0, stream>>>(
        x, eidx,
        (const float*)d_in[2],  (const float*)d_in[3],
        (const float*)d_in[4],  (const float*)d_in[5],
        (const float*)d_in[6],  (const float*)d_in[7],
        (const float*)d_in[8],  (const float*)d_in[9],
        (const float*)d_in[10], (const float*)d_in[11],
        (const float*)d_in[12], (const float*)d_in[13],
        (const float*)d_in[14], (const float*)d_in[15],
        (const float*)d_in[16], (const float*)d_in[17],
        (float*)d_out);
}

// Round 15
// 40.576 us; speedup vs baseline: 1.1112x; 1.0337x over previous
//
#include <hip/hip_runtime.h>

#define ROWS 256
#define COLS 512
#define BATCH 512
#define NC 5
#define DEG 16
#define EPG (ROWS * DEG)       /* 4096 edges per graph */
#define NPG (ROWS + COLS)      /* 768 nodes per graph  */
#define NT 512
#define EPT (EPG / NT)         /* 8 edges per thread   */
#define EPSF 1e-7f

typedef unsigned short u16;
typedef unsigned int   u32;
typedef float v2f __attribute__((ext_vector_type(2)));

__device__ __forceinline__ float sigmoid_f(float a) {
    return 1.0f / (1.0f + __expf(-a));
}
__device__ __forceinline__ float tanh_f(float a) {
    return fmaf(2.0f, 1.0f / (1.0f + __expf(-2.0f * a)), -1.0f);
}

__global__ __launch_bounds__(NT, 4) void gnni_kernel(
    const float* __restrict__ x,
    const int*   __restrict__ eidx,
    const float* __restrict__ w1_1, const float* __restrict__ b1_1,
    const float* __restrict__ w2_1, const float* __restrict__ b2_1,
    const float* __restrict__ wih_1, const float* __restrict__ whh_1,
    const float* __restrict__ bih_1, const float* __restrict__ bhh_1,
    const float* __restrict__ w1_2, const float* __restrict__ b1_2,
    const float* __restrict__ w2_2, const float* __restrict__ b2_2,
    const float* __restrict__ wih_2, const float* __restrict__ whh_2,
    const float* __restrict__ bih_2, const float* __restrict__ bhh_2,
    float* __restrict__ out)
{
    __shared__ float msg[EPG];        // per-edge messages (both phases)
    __shared__ u32  cntd[COLS];       // dst counts -> placement cursor
    __shared__ u32  cnts[ROWS];       // src counts -> placement cursor
    __shared__ u16  ofs_v[COLS + 1];  // CSR offsets per var node
    __shared__ u16  ofs_c[ROWS + 1];  // CSR offsets per check node
    __shared__ float hc[ROWS];
    __shared__ float hv[COLS];
    __shared__ u32  wsum[8];          // per-wave scan partials (dst)
    __shared__ u32  wsum2[4];         // per-wave scan partials (src)

    const int tid  = threadIdx.x;
    const int lane = tid & 63;
    const int wid  = tid >> 6;
    const int b    = blockIdx.x;
    const int base = b * NPG;
    const long ebase = (long)b * EPG;

    // ---- vectorized edge load: thread tid owns edges [tid*8, tid*8+8) ----
    const int4 sa = *(const int4*)(eidx + ebase + tid * 8);
    const int4 sb = *(const int4*)(eidx + ebase + tid * 8 + 4);
    const int4 da = *(const int4*)(eidx + (long)BATCH * EPG + ebase + tid * 8);
    const int4 db = *(const int4*)(eidx + (long)BATCH * EPG + ebase + tid * 8 + 4);
    const int sarr[EPT] = {sa.x, sa.y, sa.z, sa.w, sb.x, sb.y, sb.z, sb.w};
    const int darr[EPT] = {da.x, da.y, da.z, da.w, db.x, db.y, db.z, db.w};
    u32 ep[EPT];
    #pragma unroll
    for (int i = 0; i < EPT; ++i)
        ep[i] = (u32)(sarr[i] - base) | ((u32)(darr[i] - base) << 16);

    // ---- count both keys ----
    cntd[tid] = 0;
    if (tid < ROWS) cnts[tid] = 0;
    __syncthreads();
    #pragma unroll
    for (int i = 0; i < EPT; ++i) {
        atomicAdd(&cntd[ep[i] >> 16], 1u);
        atomicAdd(&cnts[ep[i] & 0xffffu], 1u);
    }
    __syncthreads();

    // ---- wave-shuffle scans -> exclusive cursors + CSR offsets ----
    u32 myd = cntd[tid];
    u32 scv = myd;
    #pragma unroll
    for (int st = 1; st < 64; st <<= 1) {
        u32 t = __shfl_up(scv, st);
        if (lane >= st) scv += t;
    }
    if (lane == 63) wsum[wid] = scv;
    u32 mys = 0, scc = 0;
    if (tid < ROWS) {
        mys = cnts[tid];
        scc = mys;
        #pragma unroll
        for (int st = 1; st < 64; st <<= 1) {
            u32 t = __shfl_up(scc, st);
            if (lane >= st) scc += t;
        }
        if (lane == 63) wsum2[wid] = scc;
    }
    __syncthreads();
    if (tid < 8) {
        u32 v = wsum[tid];
        #pragma unroll
        for (int st = 1; st < 8; st <<= 1) {
            u32 t = __shfl_up(v, st);
            if (tid >= st) v += t;
        }
        wsum[tid] = v;
    } else if (tid < 12) {
        u32 v = wsum2[tid - 8];
        #pragma unroll
        for (int st = 1; st < 4; st <<= 1) {
            u32 t = __shfl_up(v, st);
            if (tid - 8 >= st) v += t;
        }
        wsum2[tid - 8] = v;
    }
    __syncthreads();
    {
        u32 inc = scv + (wid ? wsum[wid - 1] : 0u);
        ofs_v[tid + 1] = (u16)inc;
        if (tid == 0) ofs_v[0] = 0;
        cntd[tid] = inc - myd;                         // exclusive cursor
    }
    if (tid < ROWS) {
        u32 inc = scc + (wid ? wsum2[wid - 1] : 0u);
        ofs_c[tid + 1] = (u16)inc;
        if (tid == 0) ofs_c[0] = 0;
        cnts[tid] = inc - mys;
        hc[tid] = x[base + tid];
    }
    float hvreg = x[base + ROWS + tid];
    hv[tid] = hvreg;
    __syncthreads();

    // ---- placement + precomputed BYTE OFFSETS (all loop-invariant, in VGPRs) ----
    u32 aS[EPT], aD[EPT], p1B[EPT], p2B[EPT];
    #pragma unroll
    for (int i = 0; i < EPT; ++i) {
        const u32 p = ep[i];
        const u32 s = p & 0xffffu;
        const u32 d = p >> 16;
        aS[i]  = s << 2;                               // byte offset into hc
        aD[i]  = d << 2;                               // byte offset into hv
        p1B[i] = atomicAdd(&cntd[d], 1u) << 2;         // byte offset into msg (phase 1)
        p2B[i] = atomicAdd(&cnts[s], 1u) << 2;         // byte offset into msg (phase 2)
    }

    // ---- weights as float2 pairs (wave-uniform -> SGPRs) ----
    v2f A1[5], C1[5], B1[5], W1[5], A2[5], C2[5], B2[5], W2[5];
    #pragma unroll
    for (int j = 0; j < 5; ++j) {
        A1[j] = (v2f){w1_1[4*j],     w1_1[4*j + 2]};
        C1[j] = (v2f){w1_1[4*j + 1], w1_1[4*j + 3]};
        B1[j] = (v2f){b1_1[2*j],     b1_1[2*j + 1]};
        W1[j] = (v2f){w2_1[2*j],     w2_1[2*j + 1]};
        A2[j] = (v2f){w1_2[4*j],     w1_2[4*j + 2]};
        C2[j] = (v2f){w1_2[4*j + 1], w1_2[4*j + 3]};
        B2[j] = (v2f){b1_2[2*j],     b1_2[2*j + 1]};
        W2[j] = (v2f){w2_2[2*j],     w2_2[2*j + 1]};
    }
    const float b2_1s = b2_1[0], b2_2s = b2_2[0];
    const v2f zero2 = (v2f){0.0f, 0.0f};
    const char* const hcB  = (const char*)hc;
    const char* const hvB  = (const char*)hv;
    char*       const msgB = (char*)msg;

    for (int it = 0; it < NC; ++it) {
        // ===== phase 1 pass A: balanced edge MLP, zero in-loop addr math =====
        #pragma unroll
        for (int i = 0; i < EPT; ++i) {
            const float xj = *(const float*)(hcB + aS[i]);
            const float xi = *(const float*)(hvB + aD[i]);
            const v2f xj2 = (v2f){xj, xj}, xi2 = (v2f){xi, xi};
            v2f acc = (v2f){b2_1s, 0.0f};
            #pragma unroll
            for (int j = 0; j < 5; ++j) {
                v2f t = __builtin_elementwise_fma(C1[j], xi2, B1[j]);
                t = __builtin_elementwise_fma(A1[j], xj2, t);
                t = __builtin_elementwise_max(t, zero2);
                acc = __builtin_elementwise_fma(W1[j], t, acc);
            }
            *(float*)(msgB + p1B[i]) = acc.x + acc.y;
        }
        __syncthreads();

        // ===== phase 1 pass B: var owner segment-sum + GRU =====
        {
            const int beg = ofs_v[tid], end = ofs_v[tid + 1];
            float hx = 0.0f;
            for (int e = beg; e < end; ++e) hx += msg[e];
            const float xg = hvreg;
            float gi0 = fmaf(wih_1[0], xg, bih_1[0]);
            float gi1 = fmaf(wih_1[1], xg, bih_1[1]);
            float gi2 = fmaf(wih_1[2], xg, bih_1[2]);
            float gh0 = fmaf(whh_1[0], hx, bhh_1[0]);
            float gh1 = fmaf(whh_1[1], hx, bhh_1[1]);
            float gh2 = fmaf(whh_1[2], hx, bhh_1[2]);
            float r = sigmoid_f(gi0 + gh0);
            float z = sigmoid_f(gi1 + gh1);
            float n = tanh_f(fmaf(r, gh2, gi2));
            hvreg = fmaf(1.0f - z, n, z * hx);
            hv[tid] = hvreg;
        }
        __syncthreads();

        // ===== phase 2 pass A: balanced edge MLP (fresh hv) =====
        #pragma unroll
        for (int i = 0; i < EPT; ++i) {
            const float xi = *(const float*)(hcB + aS[i]);
            const float xj = *(const float*)(hvB + aD[i]);
            const v2f xj2 = (v2f){xj, xj}, xi2 = (v2f){xi, xi};
            v2f acc = (v2f){b2_2s, 0.0f};
            #pragma unroll
            for (int j = 0; j < 5; ++j) {
                v2f t = __builtin_elementwise_fma(C2[j], xi2, B2[j]);
                t = __builtin_elementwise_fma(A2[j], xj2, t);
                t = __builtin_elementwise_max(t, zero2);
                acc = __builtin_elementwise_fma(W2[j], t, acc);
            }
            *(float*)(msgB + p2B[i]) = acc.x + acc.y;
        }
        __syncthreads();

        // ===== phase 2 pass B: lane-pair per check node =====
        {
            const int c    = tid >> 1;
            const int half = tid & 1;
            const int beg = ofs_c[c], end = ofs_c[c + 1];
            const int h0  = (end - beg + 1) >> 1;
            const int lo  = half ? (beg + h0) : beg;
            const int hi  = half ? end : (beg + h0);
            float part = 0.0f;
            for (int e = lo; e < hi; ++e) part += msg[e];
            part += __shfl_xor(part, 1);
            if (half == 0) {
                const float hx = part;
                const float xg = hc[c];
                float gi0 = fmaf(wih_2[0], xg, bih_2[0]);
                float gi1 = fmaf(wih_2[1], xg, bih_2[1]);
                float gi2 = fmaf(wih_2[2], xg, bih_2[2]);
                float gh0 = fmaf(whh_2[0], hx, bhh_2[0]);
                float gh1 = fmaf(whh_2[1], hx, bhh_2[1]);
                float gh2 = fmaf(whh_2[2], hx, bhh_2[2]);
                float r = sigmoid_f(gi0 + gh0);
                float z = sigmoid_f(gi1 + gh1);
                float n = tanh_f(fmaf(r, gh2, gi2));
                hc[c] = fmaf(1.0f - z, n, z * hx);
            }
        }
        __syncthreads();
    }

    // ---- epilogue: out = clip(sigmoid(-h), eps, 1-eps) ----
    {
        float sgm = 1.0f / (1.0f + __expf(hvreg));
        out[base + ROWS + tid] = fminf(fmaxf(sgm, EPSF), 1.0f - EPSF);
    }
    if (tid < ROWS) {
        float sgm = 1.0f / (1.0f + __expf(hc[tid]));
        out[base + tid] = fminf(fmaxf(sgm, EPSF), 1.0f - EPSF);
    }
}

extern "C" void kernel_launch(void* const* d_in, const int* in_sizes, int n_in,
                              void* d_out, int out_size, void* d_ws, size_t ws_size,
                              hipStream_t stream) {
    const float* x    = (const float*)d_in[0];
    const int*   eidx = (const int*)d_in[1];
    gnni_kernel<<<BATCH, NT, 0, stream>>>(
        x, eidx,
        (const float*)d_in[2],  (const float*)d_in[3],
        (const float*)d_in[4],  (const float*)d_in[5],
        (const float*)d_in[6],  (const float*)d_in[7],
        (const float*)d_in[8],  (const float*)d_in[9],
        (const float*)d_in[10], (const float*)d_in[11],
        (const float*)d_in[12], (const float*)d_in[13],
        (const float*)d_in[14], (const float*)d_in[15],
        (const float*)d_in[16], (const float*)d_in[17],
        (float*)d_out);
}